// Round 7
// baseline (2324.583 us; speedup 1.0000x reference)
//
#include <hip/hip_runtime.h>

typedef _Float16 f16;
typedef _Float16 f16x2 __attribute__((ext_vector_type(2)));
typedef _Float16 f16x4 __attribute__((ext_vector_type(4)));
typedef _Float16 f16x8 __attribute__((ext_vector_type(8)));
typedef float f32x4 __attribute__((ext_vector_type(4)));

#define N_ 256
#define T_ 64
#define D_ 1024
#define H_ 1024
#define K3 3072
#define G4 4096

// ---------------- transpose Wx/Wh/Wattn (fp32, [k][j]) -> W3T (fp16, [j][k]) -----
__global__ void k_transpose(const float* __restrict__ Wx, const float* __restrict__ Wh,
                            const float* __restrict__ Wattn, f16* __restrict__ W3T) {
    __shared__ float tile[32][33];
    int j0 = blockIdx.x * 32;   // 128 blocks over j (4096)
    int k0 = blockIdx.y * 32;   // 96 blocks over k (3072)
    int tx = threadIdx.x;       // 32
    int ty = threadIdx.y;       // 8
    for (int i = 0; i < 4; i++) {
        int k = k0 + ty + i * 8;
        const float* W = (k < 1024) ? Wx : ((k < 2048) ? Wh : Wattn);
        int kr = k & 1023;
        tile[ty + i * 8][tx] = W[(size_t)kr * 4096 + j0 + tx];
    }
    __syncthreads();
    for (int i = 0; i < 4; i++) {
        int j = j0 + ty + i * 8;
        W3T[(size_t)j * K3 + k0 + tx] = (f16)tile[tx][ty + i * 8];
    }
}

// ---------------- cast x (fp32) -> x16 (f16), 8 elems/thread ---------------------
__global__ void k_castX(const float* __restrict__ x, f16* __restrict__ x16) {
    size_t i = (size_t)blockIdx.x * 2048 + (size_t)threadIdx.x * 8;
    float4 v0 = *(const float4*)(x + i);
    float4 v1 = *(const float4*)(x + i + 4);
    f16x8 h;
    h[0] = (f16)v0.x; h[1] = (f16)v0.y; h[2] = (f16)v0.z; h[3] = (f16)v0.w;
    h[4] = (f16)v1.x; h[5] = (f16)v1.y; h[6] = (f16)v1.z; h[7] = (f16)v1.w;
    *(f16x8*)(x16 + i) = h;
}

// ---------------- A (fp32 [n][h][l]) -> A16 [n][h][l] AND AT16 [n][l][h] ---------
__global__ void k_castAT(const float* __restrict__ A, f16* __restrict__ A16,
                         f16* __restrict__ AT16) {
    __shared__ f16 sA[16 * 1024];
    int n = blockIdx.x;
    int tid = threadIdx.x;
    for (int i = 0; i < 4; i++) {
        int h = tid + i * 256;
        const float* Ap = A + (size_t)n * 16384 + h * 16;
        float4 v0 = ((const float4*)Ap)[0];
        float4 v1 = ((const float4*)Ap)[1];
        float4 v2 = ((const float4*)Ap)[2];
        float4 v3 = ((const float4*)Ap)[3];
        float vv[16] = {v0.x, v0.y, v0.z, v0.w, v1.x, v1.y, v1.z, v1.w,
                        v2.x, v2.y, v2.z, v2.w, v3.x, v3.y, v3.z, v3.w};
        f16x8 lo, hi;
#pragma unroll
        for (int l = 0; l < 8; l++) { lo[l] = (f16)vv[l]; hi[l] = (f16)vv[l + 8]; }
        *(f16x8*)(A16 + (size_t)n * 16384 + h * 16) = lo;
        *(f16x8*)(A16 + (size_t)n * 16384 + h * 16 + 8) = hi;
#pragma unroll
        for (int l = 0; l < 16; l++) sA[l * 1024 + h] = (f16)vv[l];
    }
    __syncthreads();
    for (int i = 0; i < 8; i++) {
        int cnk = tid + i * 256;     // 2048 chunks of 8 f16
        f16x8 v = *(const f16x8*)(sA + cnk * 8);
        *(f16x8*)(AT16 + (size_t)n * 16384 + cnk * 8) = v;
    }
}

// ---------------- precompute PT16[n][j][l] = sum_h A[n,h,l] * Wattn[h,j] ---------
// grid 1024 = 32 nb(8n) x 32 jb(128j); 8 waves, wave w owns 16 j-cols.
// A chunk staged in LDS (pad 268: 16 distinct banks for the 16 m16 lanes).
__global__ __launch_bounds__(512, 4) void k_precompP(
    const f16* __restrict__ AT16, const f16* __restrict__ W3T,
    f16* __restrict__ PT16) {
    __shared__ f16 As[8 * 16 * 268];      // 68.6 KB, k-dim padded 256->268
    int tid = threadIdx.x;
    int wave = tid >> 6;
    int lane = tid & 63;
    int m16 = lane & 15;
    int quad = lane >> 4;
    int bid = blockIdx.x;
    int jb = bid & 31;
    int nb = bid >> 5;
    int n0g = nb * 8;
    int j16 = jb * 128 + wave * 16;

    const f16* bp = W3T + (size_t)(j16 + m16) * K3 + 2048 + quad * 8;

    f32x4 acc[8];
#pragma unroll
    for (int n = 0; n < 8; n++) acc[n] = (f32x4){0.f, 0.f, 0.f, 0.f};

    for (int kb = 0; kb < 4; kb++) {
        __syncthreads();
        // stage A chunk: 8n x 16l x 256k = 64 KB, 4096 16B-chunks, 8 per thread
        for (int i = 0; i < 8; i++) {
            int cidx = tid + i * 512;
            int n  = cidx >> 9;
            int r  = cidx & 511;
            int l  = r >> 5;
            int kc = r & 31;
            f16x8 v = *(const f16x8*)(AT16 + (size_t)(n0g + n) * 16384 + l * 1024 + kb * 256 + kc * 8);
            *(f16x8*)(&As[(n * 16 + l) * 268 + kc * 8]) = v;
        }
        __syncthreads();
        // B chunk to registers: 8 x f16x8 (32 VGPR), read once per wave per chunk
        f16x8 bb[8];
#pragma unroll
        for (int ks = 0; ks < 8; ks++)
            bb[ks] = *(const f16x8*)(bp + kb * 256 + ks * 32);
        // 8 independent chains over n
#pragma unroll
        for (int n = 0; n < 8; n++) {
            const f16* ap = &As[(n * 16 + m16) * 268 + quad * 8];
#pragma unroll
            for (int ks = 0; ks < 8; ks++) {
                f16x8 a = *(const f16x8*)(ap + ks * 32);
                acc[n] = __builtin_amdgcn_mfma_f32_16x16x32_f16(a, bb[ks], acc[n], 0, 0, 0);
            }
        }
    }

    // C layout: col = m16 (j), row = quad*4 + r (l). 8B store per lane per n.
#pragma unroll
    for (int n = 0; n < 8; n++) {
        f16x4 o = {(f16)acc[n][0], (f16)acc[n][1], (f16)acc[n][2], (f16)acc[n][3]};
        *(f16x4*)(PT16 + (size_t)(n0g + n) * 65536 + (size_t)(j16 + m16) * 16 + quad * 4) = o;
    }
}

// ---------------- init: h0 = c0 = mean(A); Sc0[n][:] = h0.A; zero Sc1/Sc2 --------
__global__ void k_init(const float* __restrict__ A, f16* __restrict__ Zh,
                       float* __restrict__ c, float* __restrict__ Sc0,
                       float* __restrict__ Sc1, float* __restrict__ Sc2) {
    int n = blockIdx.x;
    int tid = threadIdx.x;
    __shared__ float sred[256][16];
    float s[16];
#pragma unroll
    for (int l = 0; l < 16; l++) s[l] = 0.f;
    for (int i = 0; i < 4; i++) {
        int h = tid + i * 256;
        const float* Ap = A + (size_t)n * 16384 + h * 16;
        float a[16];
        float sum = 0.f;
#pragma unroll
        for (int l = 0; l < 16; l++) { a[l] = Ap[l]; sum += a[l]; }
        float h0 = sum * (1.f / 16.f);
        c[n * 1024 + h] = h0;
        Zh[n * 1024 + h] = (f16)h0;
#pragma unroll
        for (int l = 0; l < 16; l++) s[l] += h0 * a[l];
    }
#pragma unroll
    for (int l = 0; l < 16; l++) sred[tid][l] = s[l];
    __syncthreads();
    for (int st = 128; st > 0; st >>= 1) {
        if (tid < st) {
#pragma unroll
            for (int l = 0; l < 16; l++) sred[tid][l] += sred[tid + st][l];
        }
        __syncthreads();
    }
    if (tid < 16) {
        Sc0[n * 16 + tid] = sred[0][tid];
        Sc1[n * 16 + tid] = 0.f;
        Sc2[n * 16 + tid] = 0.f;
    }
}

// ---------------- one LSTM step: softmax + GEMM(K=2048) + P-dot + state ----------
// v3: grid 512 = 8 ng(32n) x 64 ht(16 h-cols); block 512 = 8 waves; LDS 39 KB and
// VGPR<=128 (launch_bounds 512,4) -> 2 blocks/CU, 4 waves/SIMD: two independent
// blocks interleave so one block's GEMM hides the other's epilogue/sync latency.
// Rbuf: reduced scores for THIS step (complete; written by dispatch t-1).
// Wbuf: accumulate partial scores for step t+1 (atomicAdd, device scope).
// Zbuf: zeroed here (8 floats/block); it is Wbuf of step t+1.
__global__ __launch_bounds__(512, 4) void k_step(
    const f16* __restrict__ x16, const f16* __restrict__ W3T,
    const f16* __restrict__ Zin, f16* __restrict__ Zout,
    const f16* __restrict__ A16, const f16* __restrict__ PT16,
    const float* __restrict__ b, float* __restrict__ c,
    const float* __restrict__ Rbuf, float* __restrict__ Wbuf,
    float* __restrict__ Zbuf, float* __restrict__ out, int t) {
    __shared__ float Gs[4][4][32 * 17];   // 34.8 KB
    __shared__ float Hs[32 * 17];         //  2.2 KB
    __shared__ float Ws[32][17];          //  2.2 KB softmax weights

    int tid = threadIdx.x;
    int wave = tid >> 6;
    int lane = tid & 63;
    int m16 = lane & 15;
    int quad = lane >> 4;
    int bid = blockIdx.x;
    int ht = bid & 63;
    int ng = bid >> 6;
    int n0 = ng * 32;
    int hc = ht * 16;

    // ---- phase A: softmax of reduced scores (32 threads, one n each) ----
    if (tid < 32) {
        const float* rp = Rbuf + (size_t)(n0 + tid) * 16;
        float4 q0 = ((const float4*)rp)[0];
        float4 q1 = ((const float4*)rp)[1];
        float4 q2 = ((const float4*)rp)[2];
        float4 q3 = ((const float4*)rp)[3];
        float v[16] = {q0.x, q0.y, q0.z, q0.w, q1.x, q1.y, q1.z, q1.w,
                       q2.x, q2.y, q2.z, q2.w, q3.x, q3.y, q3.z, q3.w};
        float mx = -1e30f;
#pragma unroll
        for (int l = 0; l < 16; l++) { v[l] *= 0.03125f; mx = fmaxf(mx, v[l]); }
        float sum = 0.f;
#pragma unroll
        for (int l = 0; l < 16; l++) { v[l] = __expf(v[l] - mx); sum += v[l]; }
        float inv = 1.f / sum;
#pragma unroll
        for (int l = 0; l < 16; l++) Ws[tid][l] = v[l] * inv;
    }
    // zero 8 floats of the t+2 score buffer (512 blocks x 8 = 4096 entries)
    if (tid < 8) Zbuf[bid * 8 + tid] = 0.f;

    // ---- GEMM K=2048: waves 0-3 x-segment, waves 4-7 h-segment, 256 K each ----
    f32x4 acc[4][2];
#pragma unroll
    for (int g = 0; g < 4; g++)
#pragma unroll
        for (int m = 0; m < 2; m++) acc[g][m] = (f32x4){0.f, 0.f, 0.f, 0.f};

    int kb = (wave & 3) * 256;
    const f16* ab;
    size_t aoff[2];
    int bc0;
    if (wave < 4) {
        ab = x16 + (size_t)t * 1024 + kb + quad * 8;
#pragma unroll
        for (int mt = 0; mt < 2; mt++)
            aoff[mt] = (size_t)(n0 + mt * 16 + m16) * (T_ * 1024);
        bc0 = kb;
    } else {
        ab = Zin + kb + quad * 8;
#pragma unroll
        for (int mt = 0; mt < 2; mt++)
            aoff[mt] = (size_t)(n0 + mt * 16 + m16) * 1024;
        bc0 = 1024 + kb;
    }
    const f16* brow[4];
#pragma unroll
    for (int g = 0; g < 4; g++)
        brow[g] = W3T + (size_t)(g * 1024 + hc + m16) * K3 + bc0 + quad * 8;

#pragma unroll 2
    for (int s = 0; s < 8; s++) {
        int k = s * 32;
        f16x8 a[2], bb[4];
#pragma unroll
        for (int mt = 0; mt < 2; mt++) a[mt] = *(const f16x8*)(ab + aoff[mt] + k);
#pragma unroll
        for (int g = 0; g < 4; g++) bb[g] = *(const f16x8*)(brow[g] + k);
#pragma unroll
        for (int g = 0; g < 4; g++)
#pragma unroll
            for (int mt = 0; mt < 2; mt++)
                acc[g][mt] = __builtin_amdgcn_mfma_f32_16x16x32_f16(a[mt], bb[g], acc[g][mt], 0, 0, 0);
    }

    // ---- reduce 8 K-slice waves via 4 slabs: write then owner-add ----
    if (wave < 4) {
#pragma unroll
        for (int g = 0; g < 4; g++)
#pragma unroll
            for (int mt = 0; mt < 2; mt++)
#pragma unroll
                for (int r = 0; r < 4; r++)
                    Gs[wave][g][(mt * 16 + quad * 4 + r) * 17 + m16] = acc[g][mt][r];
    }
    __syncthreads();
    if (wave >= 4) {
        int sl = wave - 4;
#pragma unroll
        for (int g = 0; g < 4; g++)
#pragma unroll
            for (int mt = 0; mt < 2; mt++)
#pragma unroll
                for (int r = 0; r < 4; r++)
                    Gs[sl][g][(mt * 16 + quad * 4 + r) * 17 + m16] += acc[g][mt][r];
    }
    __syncthreads();

    // ---- gates + state: thread owns exactly one (nn, h-col), 4 gates ----
    {
        int nn = tid >> 4;
        int hh = tid & 15;
        int gi = nn * 17 + hh;
        int gn = n0 + nn;
        int gh = hc + hh;
        float wv[16];
#pragma unroll
        for (int l = 0; l < 16; l++) wv[l] = Ws[nn][l];
        // attention contribution via PT16: att(g) = sum_l wv[l]*PT[gn][g*1024+gh][l]
        float att[4];
        const f16* pt = PT16 + (size_t)gn * 65536 + (size_t)gh * 16;
#pragma unroll
        for (int g = 0; g < 4; g++) {
            const f16* p = pt + (size_t)g * 16384;
            f16x8 p0 = *(const f16x8*)(p);
            f16x8 p1 = *(const f16x8*)(p + 8);
            float s = 0.f;
#pragma unroll
            for (int l = 0; l < 8; l++)
                s += (float)p0[l] * wv[l] + (float)p1[l] * wv[l + 8];
            att[g] = s;
        }
        float ai = Gs[0][0][gi] + Gs[1][0][gi] + Gs[2][0][gi] + Gs[3][0][gi] + b[gh] + att[0];
        float af = Gs[0][1][gi] + Gs[1][1][gi] + Gs[2][1][gi] + Gs[3][1][gi] + b[1024 + gh] + att[1];
        float ao = Gs[0][2][gi] + Gs[1][2][gi] + Gs[2][2][gi] + Gs[3][2][gi] + b[2048 + gh] + att[2];
        float ag = Gs[0][3][gi] + Gs[1][3][gi] + Gs[2][3][gi] + Gs[3][3][gi] + b[3072 + gh] + att[3];
        float ig = 1.f / (1.f + __expf(-ai));
        float fg = 1.f / (1.f + __expf(-af));
        float og = 1.f / (1.f + __expf(-ao));
        float gg = tanhf(ag);
        float cn = fg * c[gn * 1024 + gh] + ig * gg;
        c[gn * 1024 + gh] = cn;
        float hn = og * tanhf(cn);
        out[((size_t)gn * T_ + t) * 1024 + gh] = hn;
        Zout[gn * 1024 + gh] = (f16)hn;
        Hs[gi] = hn;
    }
    __syncthreads();

    // ---- partial scores vs local A16 slice: 32n x 16l, 1 per thread ----
    {
        int nn = tid >> 4;
        int l = tid & 15;
        int gn = n0 + nn;
        const f16* Ap = A16 + (size_t)gn * 16384 + hc * 16 + l;
        float s = 0.f;
#pragma unroll
        for (int hh = 0; hh < 16; hh++)
            s += Hs[nn * 17 + hh] * (float)Ap[hh * 16];
        atomicAdd(Wbuf + gn * 16 + l, s);
    }
}

extern "C" void kernel_launch(void* const* d_in, const int* in_sizes, int n_in,
                              void* d_out, int out_size, void* d_ws, size_t ws_size,
                              hipStream_t stream) {
    const float* x     = (const float*)d_in[0];
    const float* A     = (const float*)d_in[1];
    const float* Wx    = (const float*)d_in[2];
    const float* Wh    = (const float*)d_in[3];
    const float* Wattn = (const float*)d_in[4];
    const float* b     = (const float*)d_in[5];
    float* out = (float*)d_out;

    char* ws = (char*)d_ws;
    size_t off = 0;
    f16* W3T  = (f16*)(ws + off); off += (size_t)G4 * K3 * 2;         // 25.2 MB
    f16* x16  = (f16*)(ws + off); off += (size_t)N_ * T_ * D_ * 2;    // 33.6 MB
    f16* A16  = (f16*)(ws + off); off += (size_t)N_ * H_ * 16 * 2;    //  8.4 MB
    f16* AT16 = (f16*)(ws + off); off += (size_t)N_ * 16 * H_ * 2;    //  8.4 MB
    f16* PT16 = (f16*)(ws + off); off += (size_t)N_ * G4 * 16 * 2;    // 33.6 MB
    f16* Zh0  = (f16*)(ws + off); off += (size_t)N_ * H_ * 2;
    f16* Zh1  = (f16*)(ws + off); off += (size_t)N_ * H_ * 2;
    float* c  = (float*)(ws + off); off += (size_t)N_ * H_ * 4;       //  1 MB
    float* Sc0 = (float*)(ws + off); off += (size_t)N_ * 16 * 4;      // 16 KB
    float* Sc1 = (float*)(ws + off); off += (size_t)N_ * 16 * 4;
    float* Sc2 = (float*)(ws + off); off += (size_t)N_ * 16 * 4;
    float* Sc[3] = {Sc0, Sc1, Sc2};

    k_transpose<<<dim3(128, 96), dim3(32, 8), 0, stream>>>(Wx, Wh, Wattn, W3T);
    k_castX<<<8192, 256, 0, stream>>>(x, x16);
    k_castAT<<<256, 256, 0, stream>>>(A, A16, AT16);
    k_precompP<<<1024, 512, 0, stream>>>(AT16, W3T, PT16);
    k_init<<<256, 256, 0, stream>>>(A, Zh0, c, Sc0, Sc1, Sc2);
    for (int t = 0; t < T_; t++) {
        f16* Zin  = (t & 1) ? Zh1 : Zh0;
        f16* Zout = (t & 1) ? Zh0 : Zh1;
        k_step<<<512, 512, 0, stream>>>(x16, W3T, Zin, Zout, A16, PT16, b, c,
                                        Sc[t % 3], Sc[(t + 1) % 3], Sc[(t + 2) % 3],
                                        out, t);
    }
}